// Round 2
// baseline (319.627 us; speedup 1.0000x reference)
//
#include <hip/hip_runtime.h>

#define E_EDGES   1000000
#define NNODES    2048
#define HCH       128
#define KPW       168                 // w1t row stride in shorts
#define TILE      64
#define NTILES    (E_EDGES / TILE)    // 15625
#define NSPREAD   8
#define GRID_GEMM 768                 // 3 blocks/CU, all resident
#define ZVEC      (32 * 2048 * 64 / 4)
#define ZBLK      512
#define ZREG      16384               // z region bytes per buffer: 64 edges x 256 B
#define AREG      80                  // attr region row stride bytes (5 x 16B chunks)
#define BUFB      (ZREG + TILE * AREG)   // 21504 B per buffer

typedef short  shortx8 __attribute__((ext_vector_type(8)));
typedef float  floatx4 __attribute__((ext_vector_type(4)));
typedef __attribute__((address_space(1))) const unsigned int GASU;
typedef __attribute__((address_space(3))) unsigned int LASU;

__device__ __forceinline__ unsigned int f2bf(float f) {
  union { float f; unsigned int u; } v; v.f = f;
  return (v.u + 0x7fffu + ((v.u >> 16) & 1u)) >> 16;   // RNE, low 16 bits valid
}

__device__ __forceinline__ void gather16(const void* gp, void* lp) {
  __builtin_amdgcn_global_load_lds((GASU*)gp, (LASU*)lp, 16, 0, 0);
}

// ---------------------------------------------------------------- prep ----
__global__ void k_prep(const float* __restrict__ z, const float* __restrict__ W1,
                       const float* __restrict__ b1,
                       unsigned short* __restrict__ zb, unsigned short* __restrict__ w1t,
                       float* __restrict__ gstats) {
  int bid = blockIdx.x;
  if (bid < ZBLK) {
    const float4* z4 = (const float4*)z;
    ushort4* zb4 = (ushort4*)zb;
    for (int i = bid * 256 + threadIdx.x; i < ZVEC; i += ZBLK * 256) {
      float4 v = z4[i];
      ushort4 o;
      o.x = (unsigned short)f2bf(v.x); o.y = (unsigned short)f2bf(v.y);
      o.z = (unsigned short)f2bf(v.z); o.w = (unsigned short)f2bf(v.w);
      zb4[i] = o;
    }
  } else if (bid == ZBLK) {
    for (int idx = threadIdx.x; idx < 132 * HCH; idx += 256) {
      int k = idx >> 7, n = idx & 127;
      w1t[n * KPW + k] = (unsigned short)f2bf(W1[idx]);
    }
    for (int idx = threadIdx.x; idx < HCH * (KPW - 132); idx += 256) {
      int n = idx / (KPW - 132);
      int k = 132 + (idx - n * (KPW - 132));
      w1t[n * KPW + k] = (k == 132) ? (unsigned short)f2bf(b1[n]) : (unsigned short)0;
    }
  } else {
    for (int i = threadIdx.x; i < NSPREAD * 2 * HCH; i += 256) gstats[i] = 0.f;
  }
}

// ---------------------------------------------------------------- gemm ----
// 64-edge tile x 128 ch, K padded to 160 (5 k-steps). 4 waves in 2x2 (eh,nh).
// B frags in registers. A double-buffered in LDS, filled by global_load_lds
// with XOR-swizzled chunk layout (conflict-free reads AND lane-contiguous
// writes). Depth-2 pipeline: idx(t+2) and gather(t+1) in flight during
// K-loop(t); ONE barrier per tile.
template<bool OUT>
__global__ __launch_bounds__(256, 3)
void k_gemm(const unsigned short* __restrict__ zb,
            const unsigned short* __restrict__ w1t,
            const int* __restrict__ ei,
            const float* __restrict__ attr,
            float* __restrict__ gstats,
            const float* __restrict__ ab,
            const float* __restrict__ W2,
            const float* __restrict__ b2,
            float* __restrict__ out) {
  __shared__ __align__(16) unsigned char Abuf[2][BUFB];   // 43008 B
  __shared__ float s_sum[HCH], s_sq[HCH];
  __shared__ float po[2][TILE];

  const int tid  = threadIdx.x;
  const int lane = tid & 63;
  const int wave = tid >> 6;
  const int l15  = lane & 15;
  const int quad = lane >> 4;
  const int eh   = wave >> 1;
  const int nh   = wave & 1;
  const int bid  = blockIdx.x;

  // ---- B fragments in registers: n = nh*64 + nt*16 + l15
  shortx8 bfr[4][5];
#pragma unroll
  for (int nt = 0; nt < 4; ++nt) {
    const unsigned short* bp = w1t + (nh * 64 + nt * 16 + l15) * KPW + quad * 8;
#pragma unroll
    for (int kk = 0; kk < 5; ++kk)
      bfr[nt][kk] = *(const shortx8*)(bp + kk * 32);
  }

  float ea[4], ebb[4], ew2[4], b2v = 0.f;
  float ssum[4] = {0.f, 0.f, 0.f, 0.f}, ssq[4] = {0.f, 0.f, 0.f, 0.f};
  if (OUT) {
#pragma unroll
    for (int nt = 0; nt < 4; ++nt) {
      int c = nh * 64 + nt * 16 + l15;
      ea[nt]  = ab[c];
      ebb[nt] = ab[HCH + c];
      ew2[nt] = W2[c];
    }
    b2v = b2[0];
  } else {
    if (tid < HCH) { s_sum[tid] = 0.f; s_sq[tid] = 0.f; }
  }

  // constant zero chunks (c=1..3) of attr region, both buffers, written once
  for (int i = tid; i < 2 * TILE * 3; i += 256) {
    int b = (i >= TILE * 3);
    int r = i - b * TILE * 3;
    int e = r / 3, c = 1 + (r - e * 3);
    *(uint4*)&Abuf[b][ZREG + e * AREG + c * 16] = (uint4){0u, 0u, 0u, 0u};
  }

  // ---- gather geometry: instr j, lanes of quad load edge ej = wave*16+j*4+quad
  const bool useDst = (l15 >= 8);      // chunk bit3 == l15 bit3
  int coff[4];                         // (c&7)*16 byte offset within zb row
#pragma unroll
  for (int j = 0; j < 4; ++j)
    coff[j] = ((l15 & 7) ^ ((j * 4 + quad) & 7)) << 4;

  // ---- A-fragment LDS byte offsets (tile-invariant; mt adds 4096 / 1280)
  int offz[5];
#pragma unroll
  for (int kk = 0; kk < 4; ++kk)
    offz[kk] = (eh * 32 + l15) * 256 + ((((kk * 4 + quad) ^ (l15 & 7))) << 4);
  offz[4] = ZREG + (eh * 32 + l15) * AREG + quad * 16;

  // ---------------- prologue ----------------
  int t = bid;
  int rowsN[4];
  {
    const int e0 = t * TILE;
#pragma unroll
    for (int j = 0; j < 4; ++j) {
      int e = wave * 16 + j * 4 + quad;
      int s = ei[e0 + e];
      int d = ei[E_EDGES + e0 + e];
      rowsN[j] = useDst ? ((s & ~(NNODES - 1)) | (d & (NNODES - 1))) : s;
    }
  }
#pragma unroll
  for (int j = 0; j < 4; ++j)
    gather16((const unsigned char*)zb + rowsN[j] * 128 + coff[j],
             &Abuf[0][wave * 4096 + j * 1024]);
  float4 av = {0.f, 0.f, 0.f, 0.f};
  if (tid < TILE) av = ((const float4*)attr)[t * TILE + tid];

  {
    int t1 = (t + GRID_GEMM < NTILES) ? t + GRID_GEMM : bid;
    const int e0 = t1 * TILE;
#pragma unroll
    for (int j = 0; j < 4; ++j) {
      int e = wave * 16 + j * 4 + quad;
      int s = ei[e0 + e];
      int d = ei[E_EDGES + e0 + e];
      rowsN[j] = useDst ? ((s & ~(NNODES - 1)) | (d & (NNODES - 1))) : s;
    }
  }
  if (tid < TILE) {
    uint4 v;
    v.x = f2bf(av.x) | (f2bf(av.y) << 16);
    v.y = f2bf(av.z) | (f2bf(av.w) << 16);
    v.z = 0x3F80u;                      // bf16(1.0) bias lane, then zeros
    v.w = 0u;
    *(uint4*)&Abuf[0][ZREG + tid * AREG] = v;
  }
  __syncthreads();                      // buf0 ready (drains gather vmcnt)

  // ---------------- main loop ----------------
  int pcur = 0;
  float prevT[2][4];
  int prevE0 = -1;

  for (; t < NTILES; t += GRID_GEMM) {
    const int pn  = pcur ^ 1;
    const int tn  = (t +     GRID_GEMM < NTILES) ? t +     GRID_GEMM : bid;
    const int tnn = (t + 2 * GRID_GEMM < NTILES) ? t + 2 * GRID_GEMM : bid;

    // 1. issue gather(tn) -> buf pn (latency hides under K-loop)
#pragma unroll
    for (int j = 0; j < 4; ++j)
      gather16((const unsigned char*)zb + rowsN[j] * 128 + coff[j],
               &Abuf[pn][wave * 4096 + j * 1024]);
    float4 avn = {0.f, 0.f, 0.f, 0.f};
    if (tid < TILE) avn = ((const float4*)attr)[tn * TILE + tid];

    // 2. idx prefetch for tnn
    int sN[4], dN[4];
    {
      const int e0 = tnn * TILE;
#pragma unroll
      for (int j = 0; j < 4; ++j) {
        int e = wave * 16 + j * 4 + quad;
        sN[j] = ei[e0 + e];
        dN[j] = ei[E_EDGES + e0 + e];
      }
    }

    // 2.5 OUT: flush previous tile's result (po written before last barrier)
    if (OUT && prevE0 >= 0 && nh == 0 && l15 == 0) {
#pragma unroll
      for (int mt = 0; mt < 2; ++mt)
#pragma unroll
        for (int r = 0; r < 4; ++r) {
          int el = eh * 32 + mt * 16 + quad * 4 + r;
          out[prevE0 + el] = prevT[mt][r] + po[pcur ^ 1][el] + b2v;
        }
    }

    // 3. K-loop on buf pcur
    floatx4 acc[2][4];
#pragma unroll
    for (int mt = 0; mt < 2; ++mt)
#pragma unroll
      for (int nt = 0; nt < 4; ++nt)
        acc[mt][nt] = (floatx4){0.f, 0.f, 0.f, 0.f};

    const unsigned char* base = &Abuf[pcur][0];
#pragma unroll
    for (int kk = 0; kk < 5; ++kk) {
      shortx8 afr0 = *(const shortx8*)(base + offz[kk]);
      shortx8 afr1 = *(const shortx8*)(base + offz[kk] + (kk < 4 ? 4096 : 1280));
#pragma unroll
      for (int nt = 0; nt < 4; ++nt) {
        acc[0][nt] = __builtin_amdgcn_mfma_f32_16x16x32_bf16(afr0, bfr[nt][kk], acc[0][nt], 0, 0, 0);
        acc[1][nt] = __builtin_amdgcn_mfma_f32_16x16x32_bf16(afr1, bfr[nt][kk], acc[1][nt], 0, 0, 0);
      }
    }

    // 4. epilogue
    if (!OUT) {
      // C/D: col = lane&15 (channel), row = quad*4 + reg (edge)
#pragma unroll
      for (int nt = 0; nt < 4; ++nt) {
        float s = 0.f, q = 0.f;
#pragma unroll
        for (int mt = 0; mt < 2; ++mt)
#pragma unroll
          for (int r = 0; r < 4; ++r) {
            float h = acc[mt][nt][r];
            s += h; q += h * h;
          }
        ssum[nt] += s; ssq[nt] += q;
      }
    } else {
      float tpart[2][4];
#pragma unroll
      for (int mt = 0; mt < 2; ++mt)
#pragma unroll
        for (int r = 0; r < 4; ++r) {
          float tv = 0.f;
#pragma unroll
          for (int nt = 0; nt < 4; ++nt) {
            float h = acc[mt][nt][r];
            float p = ea[nt] * h + ebb[nt];
            p = (p >= 0.f) ? p : 0.2f * p;
            tv += p * ew2[nt];
          }
          tv += __shfl_xor(tv, 1);
          tv += __shfl_xor(tv, 2);
          tv += __shfl_xor(tv, 4);
          tv += __shfl_xor(tv, 8);      // sum over this wave's 64 channels
          tpart[mt][r] = tv;
        }
      if (nh == 1 && l15 == 0) {
#pragma unroll
        for (int mt = 0; mt < 2; ++mt)
#pragma unroll
          for (int r = 0; r < 4; ++r)
            po[pcur][eh * 32 + mt * 16 + quad * 4 + r] = tpart[mt][r];
      }
      if (nh == 0) {
#pragma unroll
        for (int mt = 0; mt < 2; ++mt)
#pragma unroll
          for (int r = 0; r < 4; ++r)
            prevT[mt][r] = tpart[mt][r];
      }
      prevE0 = t * TILE;
    }

    // 5. attr(tn) chunk0 -> buf pn
    if (tid < TILE) {
      uint4 v;
      v.x = f2bf(avn.x) | (f2bf(avn.y) << 16);
      v.y = f2bf(avn.z) | (f2bf(avn.w) << 16);
      v.z = 0x3F80u;
      v.w = 0u;
      *(uint4*)&Abuf[pn][ZREG + tid * AREG] = v;
    }

    // 6. rows(tnn) for next iter's gather
#pragma unroll
    for (int j = 0; j < 4; ++j)
      rowsN[j] = useDst ? ((sN[j] & ~(NNODES - 1)) | (dN[j] & (NNODES - 1))) : sN[j];

    // 7. single barrier per tile (drains gather vmcnt -> buf pn complete)
    __syncthreads();
    pcur ^= 1;
  }

  if (OUT) {
    if (prevE0 >= 0 && nh == 0 && l15 == 0) {
#pragma unroll
      for (int mt = 0; mt < 2; ++mt)
#pragma unroll
        for (int r = 0; r < 4; ++r) {
          int el = eh * 32 + mt * 16 + quad * 4 + r;
          out[prevE0 + el] = prevT[mt][r] + po[pcur ^ 1][el] + b2v;
        }
    }
  } else {
#pragma unroll
    for (int nt = 0; nt < 4; ++nt) {
      float s = ssum[nt], q = ssq[nt];
      s += __shfl_xor(s, 16); s += __shfl_xor(s, 32);
      q += __shfl_xor(q, 16); q += __shfl_xor(q, 32);
      if (quad == 0) {
        atomicAdd(&s_sum[nh * 64 + nt * 16 + l15], s);
        atomicAdd(&s_sq [nh * 64 + nt * 16 + l15], q);
      }
    }
    __syncthreads();
    float* dstc = gstats + (bid & (NSPREAD - 1)) * 2 * HCH;
    if (tid < HCH)          atomicAdd(&dstc[tid], s_sum[tid]);
    else if (tid < 2 * HCH) atomicAdd(&dstc[tid], s_sq[tid - HCH]);
  }
}

// --------------------------------------------------------------- final ----
__global__ void k_final(const float* __restrict__ gstats,
                        const float* __restrict__ gamma,
                        const float* __restrict__ beta,
                        float* __restrict__ ab) {
  int c = threadIdx.x;
  if (c < HCH) {
    float S = 0.f, Q = 0.f;
    for (int i = 0; i < NSPREAD; ++i) {
      S += gstats[i * 2 * HCH + c];
      Q += gstats[i * 2 * HCH + HCH + c];
    }
    float inv = 1.0f / (float)E_EDGES;
    float mu = S * inv;
    float var = Q * inv - mu * mu;
    float rstd = rsqrtf(var + 1e-5f);
    float a = gamma[c] * rstd;
    ab[c] = a;
    ab[HCH + c] = beta[c] - mu * a;
  }
}

// -------------------------------------------------------------- launch ----
extern "C" void kernel_launch(void* const* d_in, const int* in_sizes, int n_in,
                              void* d_out, int out_size, void* d_ws, size_t ws_size,
                              hipStream_t stream) {
  const float* z     = (const float*)d_in[0];
  const float* attr  = (const float*)d_in[1];
  const float* W1    = (const float*)d_in[2];
  const float* b1    = (const float*)d_in[3];
  const float* gamma = (const float*)d_in[4];
  const float* beta  = (const float*)d_in[5];
  const float* W2    = (const float*)d_in[6];
  const float* b2    = (const float*)d_in[7];
  const int*   ei    = (const int*)d_in[8];
  float* out = (float*)d_out;

  char* ws = (char*)d_ws;
  unsigned short* zb  = (unsigned short*)ws;                 // 8,388,608 B
  unsigned short* w1t = (unsigned short*)(ws + 8388608);     //    43,008 B
  float* gstats       = (float*)(ws + 8431616);              //     8,192 B
  float* ab           = (float*)(ws + 8439808);              //     1,024 B

  k_prep<<<ZBLK + 2, 256, 0, stream>>>(z, W1, b1, zb, w1t, gstats);
  k_gemm<false><<<GRID_GEMM, 256, 0, stream>>>(zb, w1t, ei, attr, gstats,
                                               nullptr, W2, b2, nullptr);
  k_final<<<1, 128, 0, stream>>>(gstats, gamma, beta, ab);
  k_gemm<true><<<GRID_GEMM, 256, 0, stream>>>(zb, w1t, ei, attr, gstats,
                                              ab, W2, b2, out);
}

// Round 3
// 269.742 us; speedup vs baseline: 1.1849x; 1.1849x over previous
//
#include <hip/hip_runtime.h>

#define E_EDGES   1000000
#define NNODES    2048
#define HCH       128
#define KPW       168                 // LDS A row stride in shorts (336 B)
#define TILE      64
#define NTILES    (E_EDGES / TILE)    // 15625
#define NSPREAD   8
#define GRID_GEMM 768                 // ~3 blocks/CU resident (LDS/VGPR bound)
#define ZVEC      (32 * 2048 * 64 / 4)
#define ZBLK      512

typedef short  shortx8 __attribute__((ext_vector_type(8)));
typedef float  floatx4 __attribute__((ext_vector_type(4)));

__device__ __forceinline__ unsigned int f2bf(float f) {
  union { float f; unsigned int u; } v; v.f = f;
  return (v.u + 0x7fffu + ((v.u >> 16) & 1u)) >> 16;   // RNE, low 16 bits valid
}

// ---------------------------------------------------------------- prep ----
__global__ void k_prep(const float* __restrict__ z, const float* __restrict__ W1,
                       const float* __restrict__ b1,
                       unsigned short* __restrict__ zb, unsigned short* __restrict__ w1t,
                       float* __restrict__ gstats) {
  int bid = blockIdx.x;
  if (bid < ZBLK) {
    const float4* z4 = (const float4*)z;
    ushort4* zb4 = (ushort4*)zb;
    for (int i = bid * 256 + threadIdx.x; i < ZVEC; i += ZBLK * 256) {
      float4 v = z4[i];
      ushort4 o;
      o.x = (unsigned short)f2bf(v.x); o.y = (unsigned short)f2bf(v.y);
      o.z = (unsigned short)f2bf(v.z); o.w = (unsigned short)f2bf(v.w);
      zb4[i] = o;
    }
  } else if (bid == ZBLK) {
    for (int idx = threadIdx.x; idx < 132 * HCH; idx += 256) {
      int k = idx >> 7, n = idx & 127;
      w1t[n * KPW + k] = (unsigned short)f2bf(W1[idx]);
    }
    for (int idx = threadIdx.x; idx < HCH * (KPW - 132); idx += 256) {
      int n = idx / (KPW - 132);
      int k = 132 + (idx - n * (KPW - 132));
      w1t[n * KPW + k] = (k == 132) ? (unsigned short)f2bf(b1[n]) : (unsigned short)0;
    }
  } else {
    for (int i = threadIdx.x; i < NSPREAD * 2 * HCH; i += 256) gstats[i] = 0.f;
  }
}

// ---------------------------------------------------------------- gemm ----
// 64-edge tile x 128 ch, K padded to 160 (5 k-steps). 4 waves in 2x2 (eh,nh).
// B frags in registers. A double-buffered in LDS. Gather goes through
// VGPRs (L1/L2-cached, unlike LDS-DMA which tripled FETCH in R2); loads for
// tile t+1 are issued before tile t's K-loop so latency hides under MFMA.
// ONE barrier per tile. OUT pass folds the BN-coefficient finalize in.
template<bool OUT>
__global__ __launch_bounds__(256, 3)
void k_gemm(const unsigned short* __restrict__ zb,
            const unsigned short* __restrict__ w1t,
            const int* __restrict__ ei,
            const float* __restrict__ attr,
            float* __restrict__ gstats,
            const float* __restrict__ gamma,
            const float* __restrict__ beta,
            const float* __restrict__ W2,
            const float* __restrict__ b2,
            float* __restrict__ out) {
  __shared__ __align__(16) unsigned short A[2][TILE * KPW];   // 43008 B
  __shared__ float s_sum[HCH], s_sq[HCH];
  __shared__ float po[2][TILE];

  const int tid  = threadIdx.x;
  const int lane = tid & 63;
  const int wave = tid >> 6;
  const int l15  = lane & 15;
  const int quad = lane >> 4;
  const int eh   = wave >> 1;
  const int nh   = wave & 1;
  const int bid  = blockIdx.x;
  const int eloc = tid >> 2;          // edge within tile this thread stages
  const int q    = tid & 3;           // q>>1: src/dst, q&1: which 64B half

  // ---- B fragments in registers: n = nh*64 + nt*16 + l15
  shortx8 bfr[4][5];
#pragma unroll
  for (int nt = 0; nt < 4; ++nt) {
    const unsigned short* bp = w1t + (nh * 64 + nt * 16 + l15) * KPW + quad * 8;
#pragma unroll
    for (int kk = 0; kk < 5; ++kk)
      bfr[nt][kk] = *(const shortx8*)(bp + kk * 32);
  }

  float ea[4], ebb[4], ew2[4], b2v = 0.f;
  float ssum[4] = {0.f, 0.f, 0.f, 0.f}, ssq[4] = {0.f, 0.f, 0.f, 0.f};
  if (OUT) {
    // fold k_final: reduce the NSPREAD gstats copies and build BN coeffs
#pragma unroll
    for (int nt = 0; nt < 4; ++nt) {
      int c = nh * 64 + nt * 16 + l15;
      float S = 0.f, Q = 0.f;
#pragma unroll
      for (int i = 0; i < NSPREAD; ++i) {
        S += gstats[i * 2 * HCH + c];
        Q += gstats[i * 2 * HCH + HCH + c];
      }
      float inv = 1.0f / (float)E_EDGES;
      float mu  = S * inv;
      float var = Q * inv - mu * mu;
      float a   = gamma[c] * rsqrtf(var + 1e-5f);
      ea[nt]  = a;
      ebb[nt] = beta[c] - mu * a;
      ew2[nt] = W2[c];
    }
    b2v = b2[0];
  } else {
    if (tid < HCH) { s_sum[tid] = 0.f; s_sq[tid] = 0.f; }
  }

  // zero the constant K-pad region (k=136..167 -> bytes 272..335), both bufs
  for (int i = tid; i < 2 * TILE * 4; i += 256) {
    int b = i >> 8, r = (i >> 2) & 63, c = i & 3;
    *(uint4*)((char*)&A[b][r * KPW] + 272 + c * 16) = (uint4){0u, 0u, 0u, 0u};
  }

  // ---------------- prologue: fill buf0 with tile t0 ----------------
  int t = bid;
  int rowN;        // this thread's gather row for the NEXT tile
  uint4 st[4];
  float4 av = {0.f, 0.f, 0.f, 0.f};
  {
    int s = ei[t * TILE + eloc];
    int d = ei[E_EDGES + t * TILE + eloc];
    int row = (q >= 2) ? ((s & ~(NNODES - 1)) | (d & (NNODES - 1))) : s;
    const uint4* src = (const uint4*)((const char*)zb + row * 128 + (q & 1) * 64);
    st[0] = src[0]; st[1] = src[1]; st[2] = src[2]; st[3] = src[3];
    if (tid < TILE) av = ((const float4*)attr)[t * TILE + tid];
  }
  {
    int t1 = (t + GRID_GEMM < NTILES) ? t + GRID_GEMM : bid;
    int s = ei[t1 * TILE + eloc];
    int d = ei[E_EDGES + t1 * TILE + eloc];
    rowN = (q >= 2) ? ((s & ~(NNODES - 1)) | (d & (NNODES - 1))) : s;
  }
  {
    char* dst = (char*)&A[0][eloc * KPW] + q * 64;
    ((uint4*)dst)[0] = st[0]; ((uint4*)dst)[1] = st[1];
    ((uint4*)dst)[2] = st[2]; ((uint4*)dst)[3] = st[3];
    if (tid < TILE) {
      uint4 v;
      v.x = f2bf(av.x) | (f2bf(av.y) << 16);
      v.y = f2bf(av.z) | (f2bf(av.w) << 16);
      v.z = 0x3F80u;                  // bf16(1.0) bias lane + zeros
      v.w = 0u;
      *(uint4*)((char*)&A[0][tid * KPW] + 256) = v;
    }
  }
  __syncthreads();

  // ---------------- main loop ----------------
  int pcur = 0;
  float prevT[2][4];
  int prevE0 = -1;

  for (; t < NTILES; t += GRID_GEMM) {
    const int pn  = pcur ^ 1;
    const int tn  = (t +     GRID_GEMM < NTILES) ? t +     GRID_GEMM : bid;
    const int tnn = (t + 2 * GRID_GEMM < NTILES) ? t + 2 * GRID_GEMM : bid;

    // 1. issue gather(tn) into VGPRs -- latency hides under the K-loop
    {
      const uint4* src = (const uint4*)((const char*)zb + rowN * 128 + (q & 1) * 64);
      st[0] = src[0]; st[1] = src[1]; st[2] = src[2]; st[3] = src[3];
    }
    float4 avn = {0.f, 0.f, 0.f, 0.f};
    if (tid < TILE) avn = ((const float4*)attr)[tn * TILE + tid];

    // 2. idx prefetch for tnn
    int sN = ei[tnn * TILE + eloc];
    int dN = ei[E_EDGES + tnn * TILE + eloc];

    // 2.5 OUT: flush previous tile's result
    if (OUT && prevE0 >= 0 && nh == 0 && l15 == 0) {
#pragma unroll
      for (int mt = 0; mt < 2; ++mt)
#pragma unroll
        for (int r = 0; r < 4; ++r) {
          int el = eh * 32 + mt * 16 + quad * 4 + r;
          out[prevE0 + el] = prevT[mt][r] + po[pcur ^ 1][el] + b2v;
        }
    }

    // 3. K-loop on buf pcur
    floatx4 acc[2][4];
#pragma unroll
    for (int mt = 0; mt < 2; ++mt)
#pragma unroll
      for (int nt = 0; nt < 4; ++nt)
        acc[mt][nt] = (floatx4){0.f, 0.f, 0.f, 0.f};

#pragma unroll
    for (int kk = 0; kk < 5; ++kk) {
      shortx8 afr0 = *(const shortx8*)(&A[pcur][(eh * 32 + l15) * KPW + kk * 32 + quad * 8]);
      shortx8 afr1 = *(const shortx8*)(&A[pcur][(eh * 32 + 16 + l15) * KPW + kk * 32 + quad * 8]);
#pragma unroll
      for (int nt = 0; nt < 4; ++nt) {
        acc[0][nt] = __builtin_amdgcn_mfma_f32_16x16x32_bf16(afr0, bfr[nt][kk], acc[0][nt], 0, 0, 0);
        acc[1][nt] = __builtin_amdgcn_mfma_f32_16x16x32_bf16(afr1, bfr[nt][kk], acc[1][nt], 0, 0, 0);
      }
    }

    // 4. epilogue (C/D: col = lane&15 = channel, row = quad*4 + reg = edge)
    if (!OUT) {
#pragma unroll
      for (int nt = 0; nt < 4; ++nt) {
        float s = 0.f, qq = 0.f;
#pragma unroll
        for (int mt = 0; mt < 2; ++mt)
#pragma unroll
          for (int r = 0; r < 4; ++r) {
            float h = acc[mt][nt][r];
            s += h; qq += h * h;
          }
        ssum[nt] += s; ssq[nt] += qq;
      }
    } else {
      float tpart[2][4];
#pragma unroll
      for (int mt = 0; mt < 2; ++mt)
#pragma unroll
        for (int r = 0; r < 4; ++r) {
          float tv = 0.f;
#pragma unroll
          for (int nt = 0; nt < 4; ++nt) {
            float h = acc[mt][nt][r];
            float p = ea[nt] * h + ebb[nt];
            p = (p >= 0.f) ? p : 0.2f * p;
            tv += p * ew2[nt];
          }
          tv += __shfl_xor(tv, 1);
          tv += __shfl_xor(tv, 2);
          tv += __shfl_xor(tv, 4);
          tv += __shfl_xor(tv, 8);      // sum over this wave's 64 channels
          tpart[mt][r] = tv;
        }
      if (nh == 1 && l15 == 0) {
#pragma unroll
        for (int mt = 0; mt < 2; ++mt)
#pragma unroll
          for (int r = 0; r < 4; ++r)
            po[pcur][eh * 32 + mt * 16 + quad * 4 + r] = tpart[mt][r];
      }
      if (nh == 0) {
#pragma unroll
        for (int mt = 0; mt < 2; ++mt)
#pragma unroll
          for (int r = 0; r < 4; ++r)
            prevT[mt][r] = tpart[mt][r];
      }
      prevE0 = t * TILE;
    }

    // 5. compute rows(tnn) for next iteration's gather
    rowN = (q >= 2) ? ((sN & ~(NNODES - 1)) | (dN & (NNODES - 1))) : sN;

    // 6. stage VGPRs -> LDS buf pn (waits on the gather issued in step 1)
    {
      char* dst = (char*)&A[pn][eloc * KPW] + q * 64;
      ((uint4*)dst)[0] = st[0]; ((uint4*)dst)[1] = st[1];
      ((uint4*)dst)[2] = st[2]; ((uint4*)dst)[3] = st[3];
      if (tid < TILE) {
        uint4 v;
        v.x = f2bf(avn.x) | (f2bf(avn.y) << 16);
        v.y = f2bf(avn.z) | (f2bf(avn.w) << 16);
        v.z = 0x3F80u;
        v.w = 0u;
        *(uint4*)((char*)&A[pn][tid * KPW] + 256) = v;
      }
    }

    // 7. single barrier per tile
    __syncthreads();
    pcur ^= 1;
  }

  if (OUT) {
    if (prevE0 >= 0 && nh == 0 && l15 == 0) {
#pragma unroll
      for (int mt = 0; mt < 2; ++mt)
#pragma unroll
        for (int r = 0; r < 4; ++r) {
          int el = eh * 32 + mt * 16 + quad * 4 + r;
          out[prevE0 + el] = prevT[mt][r] + po[pcur ^ 1][el] + b2v;
        }
    }
  } else {
#pragma unroll
    for (int nt = 0; nt < 4; ++nt) {
      float s = ssum[nt], qv = ssq[nt];
      s += __shfl_xor(s, 16); s += __shfl_xor(s, 32);
      qv += __shfl_xor(qv, 16); qv += __shfl_xor(qv, 32);
      if (quad == 0) {
        atomicAdd(&s_sum[nh * 64 + nt * 16 + l15], s);
        atomicAdd(&s_sq [nh * 64 + nt * 16 + l15], qv);
      }
    }
    __syncthreads();
    float* dstc = gstats + (bid & (NSPREAD - 1)) * 2 * HCH;
    if (tid < HCH)          atomicAdd(&dstc[tid], s_sum[tid]);
    else if (tid < 2 * HCH) atomicAdd(&dstc[tid], s_sq[tid - HCH]);
  }
}

// -------------------------------------------------------------- launch ----
extern "C" void kernel_launch(void* const* d_in, const int* in_sizes, int n_in,
                              void* d_out, int out_size, void* d_ws, size_t ws_size,
                              hipStream_t stream) {
  const float* z     = (const float*)d_in[0];
  const float* attr  = (const float*)d_in[1];
  const float* W1    = (const float*)d_in[2];
  const float* b1    = (const float*)d_in[3];
  const float* gamma = (const float*)d_in[4];
  const float* beta  = (const float*)d_in[5];
  const float* W2    = (const float*)d_in[6];
  const float* b2    = (const float*)d_in[7];
  const int*   ei    = (const int*)d_in[8];
  float* out = (float*)d_out;

  char* ws = (char*)d_ws;
  unsigned short* zb  = (unsigned short*)ws;                 // 8,388,608 B
  unsigned short* w1t = (unsigned short*)(ws + 8388608);     //    43,008 B
  float* gstats       = (float*)(ws + 8431616);              //     8,192 B

  k_prep<<<ZBLK + 2, 256, 0, stream>>>(z, W1, b1, zb, w1t, gstats);
  k_gemm<false><<<GRID_GEMM, 256, 0, stream>>>(zb, w1t, ei, attr, gstats,
                                               gamma, beta, W2, b2, nullptr);
  k_gemm<true><<<GRID_GEMM, 256, 0, stream>>>(zb, w1t, ei, attr, gstats,
                                              gamma, beta, W2, b2, out);
}